// Round 3
// baseline (735.444 us; speedup 1.0000x reference)
//
#include <hip/hip_runtime.h>
#include <cstdint>

#define T_TOK 1024
#define HID   2048
#define NEXP  64
#define TOPK  8
#define INTER 768

typedef __attribute__((ext_vector_type(8))) short short8;   // 8 x bf16 (4 VGPRs)
typedef __attribute__((ext_vector_type(4))) float f32x4;

__device__ __forceinline__ unsigned short f2bf(float f){
  unsigned u = __float_as_uint(f);
  u += 0x7FFFu + ((u >> 16) & 1u);   // RNE; inputs are finite
  return (unsigned short)(u >> 16);
}

// ---------------- kernel 1: x (fp32) -> bf16 once per launch ----------------
__global__ void k_convert_x(const float* __restrict__ x, unsigned short* __restrict__ xbf){
  int gid = blockIdx.x * 256 + threadIdx.x;
  const float4* src = (const float4*)(x + (size_t)gid * 8);
  float4 a = src[0], b = src[1];
  uint4 p;
  p.x = f2bf(a.x) | ((unsigned)f2bf(a.y) << 16);
  p.y = f2bf(a.z) | ((unsigned)f2bf(a.w) << 16);
  p.z = f2bf(b.x) | ((unsigned)f2bf(b.y) << 16);
  p.w = f2bf(b.z) | ((unsigned)f2bf(b.w) << 16);
  *(uint4*)(xbf + (size_t)gid * 8) = p;
}

// ---------------- kernel 2: router (fp32-exact logits, top-8) ----------------
__global__ void k_router(const float* __restrict__ x, const float* __restrict__ gw,
                         int* __restrict__ top_idx, float* __restrict__ top_w){
  int t = blockIdx.x;
  int tid = threadIdx.x;
  __shared__ float  xs[HID];
  __shared__ double part[4][NEXP];
  for (int i = tid; i < HID; i += 256) xs[i] = x[(size_t)t * HID + i];
  __syncthreads();
  int e = tid & 63, q = tid >> 6;
  double acc = 0.0;
  const float* gp = gw + e;
  #pragma unroll 8
  for (int h = q * 512; h < q * 512 + 512; ++h)
    acc += (double)xs[h] * (double)gp[(size_t)h * NEXP];
  part[q][e] = acc;
  __syncthreads();
  if (tid < 64){
    float logit = (float)(part[0][e] + part[1][e] + part[2][e] + part[3][e]);
    float cur = logit;
    float vals[TOPK]; int idxs[TOPK];
    #pragma unroll
    for (int k = 0; k < TOPK; ++k){
      float m = cur; int mi = e;
      #pragma unroll
      for (int off = 32; off > 0; off >>= 1){
        float ov = __shfl_xor(m, off);
        int   oi = __shfl_xor(mi, off);
        if (ov > m || (ov == m && oi < mi)){ m = ov; mi = oi; }
      }
      vals[k] = m; idxs[k] = mi;
      if (e == mi) cur = -1e30f;
    }
    float mx = vals[0], s = 0.f, ev[TOPK];
    #pragma unroll
    for (int k = 0; k < TOPK; ++k){ ev[k] = expf(vals[k] - mx); s += ev[k]; }
    #pragma unroll
    for (int k = 0; k < TOPK; ++k)
      if (e == k){ top_idx[t * TOPK + k] = idxs[k]; top_w[t * TOPK + k] = ev[k] / s; }
  }
}

// ---------------- kernel 3: per-expert histogram + exclusive scan ----------------
__global__ void k_hist(const int* __restrict__ top_idx, int* __restrict__ offs){
  __shared__ int hist[NEXP];
  int tid = threadIdx.x;
  if (tid < NEXP) hist[tid] = 0;
  __syncthreads();
  for (int j = tid; j < T_TOK * TOPK; j += 256) atomicAdd(&hist[top_idx[j]], 1);
  __syncthreads();
  if (tid == 0){
    int run = 0;
    for (int e = 0; e < NEXP; ++e){ offs[e] = run; run += hist[e]; }
    offs[NEXP] = run;
  }
}

// ---------------- kernel 4: deterministic ordered compaction ----------------
__global__ void k_compact(const int* __restrict__ top_idx, const float* __restrict__ top_w,
                          const int* __restrict__ offs, int* __restrict__ list_t,
                          float* __restrict__ list_w, int* __restrict__ slot_of){
  int e = blockIdx.x, tid = threadIdx.x;
  __shared__ int sc[256];
  int j0 = tid * 32, cnt = 0;
  for (int jj = 0; jj < 32; ++jj) cnt += (top_idx[j0 + jj] == e);
  sc[tid] = cnt; __syncthreads();
  for (int d = 1; d < 256; d <<= 1){
    int v = (tid >= d) ? sc[tid - d] : 0;
    __syncthreads();
    sc[tid] += v;
    __syncthreads();
  }
  int pos = offs[e] + sc[tid] - cnt;
  for (int jj = 0; jj < 32; ++jj){
    int j = j0 + jj;
    if (top_idx[j] == e){
      list_t[pos]  = j >> 3;
      list_w[pos]  = top_w[j];
      slot_of[j]   = pos;
      ++pos;
    }
  }
}

#define BARRIER() do { asm volatile("s_waitcnt lgkmcnt(0)" ::: "memory"); \
                       __builtin_amdgcn_s_barrier(); } while (0)

// ---------------- kernel 5: gate/up GEMM + SwiGLU ----------------
// BM=192 (whole expert), BN=64i x {gate,up}, BK=64, KT=32. 512 thr = 8 waves (4m x 2n).
// 3 B-register sets + 3 LDS buffers: WRITE_B(t+2) at body t waits loads issued at
// body t-2 (2 full tiles of cover). A issued body-ahead into a 2-set rotation,
// BEFORE the B issue so A-waits never transitively drain the youngest B batch
// (vmcnt retires in order). One barrier per tile.
__global__ __launch_bounds__(512, 2) void k_gateup(
    const unsigned short* __restrict__ xbf, const float* __restrict__ wg,
    const float* __restrict__ wu, const int* __restrict__ offs,
    const int* __restrict__ list_t, const float* __restrict__ list_w,
    unsigned short* __restrict__ act){
  const int KT = HID / 64;                   // 32 k-tiles
  int owner = blockIdx.x;                    // 768 = 12 i-tiles x 64 experts
  int hi = owner >> 3;
  int e  = (owner & 7) + ((hi / 12) << 3);   // all 12 i-blocks of an expert on one XCD
  int i0 = (hi % 12) * 64;
  int beg = offs[e], n_e = offs[e + 1] - beg;
  if (n_e <= 0) return;
  int tid = threadIdx.x, lane = tid & 63, wid = tid >> 6;
  int wm = wid & 3, wn = wid >> 2;           // 48-row m-quarter, 32-col n-half

  __shared__ unsigned short lB[3][2][64 * 64];   // 3 bufs x 2 mats x 8KB = 48 KB

  int bi = tid & 63, bg = tid >> 6;
  int bswz = (bi & 7) << 4;
  const float* gBase = wg + (size_t)e * HID * INTER + i0 + bi;
  const float* uBase = wu + (size_t)e * HID * INTER + i0 + bi;

#define GU_ISSUE_B(t, rg_, ru_) { \
    const float* _gp = gBase + (size_t)((t) * 64 + bg * 8) * INTER; \
    const float* _up = uBase + (size_t)((t) * 64 + bg * 8) * INTER; \
    _Pragma("unroll") for (int j = 0; j < 8; ++j){ \
      rg_[j] = _gp[(size_t)j * INTER]; ru_[j] = _up[(size_t)j * INTER]; } }

#define GU_WRITE_B(buf, rg_, ru_) { \
    uint4 _p; \
    _p.x = f2bf(rg_[0]) | ((unsigned)f2bf(rg_[1]) << 16); \
    _p.y = f2bf(rg_[2]) | ((unsigned)f2bf(rg_[3]) << 16); \
    _p.z = f2bf(rg_[4]) | ((unsigned)f2bf(rg_[5]) << 16); \
    _p.w = f2bf(rg_[6]) | ((unsigned)f2bf(rg_[7]) << 16); \
    *(uint4*)((char*)&lB[buf][0][0] + bi * 128 + ((bg * 16) ^ bswz)) = _p; \
    _p.x = f2bf(ru_[0]) | ((unsigned)f2bf(ru_[1]) << 16); \
    _p.y = f2bf(ru_[2]) | ((unsigned)f2bf(ru_[3]) << 16); \
    _p.z = f2bf(ru_[4]) | ((unsigned)f2bf(ru_[5]) << 16); \
    _p.w = f2bf(ru_[6]) | ((unsigned)f2bf(ru_[7]) << 16); \
    *(uint4*)((char*)&lB[buf][1][0] + bi * 128 + ((bg * 16) ^ bswz)) = _p; }

#define GU_ISSUE_A(t, ra_) { \
    int _kk = (t) * 64 + ((lane >> 4) << 3); \
    _Pragma("unroll") for (int mf = 0; mf < 3; ++mf){ \
      const unsigned short* _ap = xbf + (size_t)tokA[mf] * HID + _kk; \
      ra_[mf][0] = *(const short8*)_ap; \
      ra_[mf][1] = *(const short8*)(_ap + 32); } }

#define GU_MFMA(buf, ra_) { \
    _Pragma("unroll") for (int ks = 0; ks < 2; ++ks){ \
      short8 _bf[2][2]; \
      _Pragma("unroll") for (int nf = 0; nf < 2; ++nf){ \
        int _il = wn * 32 + nf * 16 + (lane & 15); \
        int _kb = (ks * 64 + ((lane >> 4) << 4)) ^ ((_il & 7) << 4); \
        _bf[0][nf] = *(const short8*)((const char*)&lB[buf][0][0] + _il * 128 + _kb); \
        _bf[1][nf] = *(const short8*)((const char*)&lB[buf][1][0] + _il * 128 + _kb); } \
      _Pragma("unroll") for (int mf = 0; mf < 3; ++mf) \
        _Pragma("unroll") for (int nf = 0; nf < 2; ++nf){ \
          accg[mf][nf] = __builtin_amdgcn_mfma_f32_16x16x32_bf16(ra_[mf][ks], _bf[0][nf], accg[mf][nf], 0, 0, 0); \
          accu[mf][nf] = __builtin_amdgcn_mfma_f32_16x16x32_bf16(ra_[mf][ks], _bf[1][nf], accu[mf][nf], 0, 0, 0); } } }

// body t: A(t+1)->rA[ANXT]; B(t+4)->set SI=(t+1)%3; MFMA lds[t%3] w/ rA[ACUR];
//         WRITE set SW=(t+2)%3 -> lds[(t+2)%3]; barrier.
#define GU_BODY(T, ACUR, ANXT, SI, SW, LR, LW, DO_A, DO_B, DO_W) { \
    if (DO_A) GU_ISSUE_A((T) + 1, rA[ANXT]); \
    if (DO_B) GU_ISSUE_B((T) + 4, rg[SI], ru[SI]); \
    GU_MFMA(LR, rA[ACUR]); \
    if (DO_W) GU_WRITE_B(LW, rg[SW], ru[SW]); \
    BARRIER(); }

  for (int m0 = 0; m0 < n_e; m0 += 192){
    int tokA[3];
    #pragma unroll
    for (int mf = 0; mf < 3; ++mf){
      int r = wm * 48 + mf * 16 + (lane & 15);
      tokA[mf] = list_t[(m0 + r < n_e) ? (beg + m0 + r) : beg];
    }
    float rg[3][8], ru[3][8];
    short8 rA[2][3][2];
    f32x4 accg[3][2] = {}; f32x4 accu[3][2] = {};

    GU_ISSUE_B(0, rg[0], ru[0]);
    GU_ISSUE_B(1, rg[1], ru[1]);
    GU_ISSUE_B(2, rg[2], ru[2]);
    GU_ISSUE_A(0, rA[0]);
    GU_WRITE_B(0, rg[0], ru[0]);      // one full-latency stall per pass (prologue only)
    GU_WRITE_B(1, rg[1], ru[1]);
    GU_ISSUE_B(3, rg[0], ru[0]);
    BARRIER();

    #pragma unroll 1
    for (int t = 0; t < 24; t += 6){
      GU_BODY(t + 0, 0, 1, 1, 2, 0, 2, 1, 1, 1);
      GU_BODY(t + 1, 1, 0, 2, 0, 1, 0, 1, 1, 1);
      GU_BODY(t + 2, 0, 1, 0, 1, 2, 1, 1, 1, 1);
      GU_BODY(t + 3, 1, 0, 1, 2, 0, 2, 1, 1, 1);
      GU_BODY(t + 4, 0, 1, 2, 0, 1, 0, 1, 1, 1);
      GU_BODY(t + 5, 1, 0, 0, 1, 2, 1, 1, 1, 1);
    }
    GU_BODY(24, 0, 1, 1, 2, 0, 2, 1, 1, 1);
    GU_BODY(25, 1, 0, 2, 0, 1, 0, 1, 1, 1);
    GU_BODY(26, 0, 1, 0, 1, 2, 1, 1, 1, 1);
    GU_BODY(27, 1, 0, 1, 2, 0, 2, 1, 1, 1);   // issues B31 (last)
    GU_BODY(28, 0, 1, 2, 0, 1, 0, 1, 0, 1);
    GU_BODY(29, 1, 0, 0, 1, 2, 1, 1, 0, 1);   // writes B31 (last)
    GU_BODY(30, 0, 1, 1, 2, 0, 2, 1, 0, 0);
    GU_BODY(31, 1, 0, 2, 0, 1, 0, 0, 0, 0);

    // epilogue: SwiGLU * routing weight -> bf16
    #pragma unroll
    for (int mf = 0; mf < 3; ++mf){
      #pragma unroll
      for (int rr = 0; rr < 4; ++rr){
        int r = wm * 48 + mf * 16 + ((lane >> 4) << 2) + rr;
        if (m0 + r < n_e){
          int slot = beg + m0 + r;
          float wgt = list_w[slot];
          #pragma unroll
          for (int nf = 0; nf < 2; ++nf){
            float g = accg[mf][nf][rr], u = accu[mf][nf][rr];
            float h = (g / (1.f + expf(-g))) * u * wgt;
            act[(size_t)slot * INTER + i0 + wn * 32 + nf * 16 + (lane & 15)] = f2bf(h);
          }
        }
      }
    }
  }
}

// ---------------- kernel 6: down-proj GEMM ----------------
// BM=192, BN=128 h-cols, BK=64, KT=12. Same 3-set/3-buf pipeline.
__global__ __launch_bounds__(512, 2) void k_down(
    const unsigned short* __restrict__ act, const float* __restrict__ wd,
    const int* __restrict__ offs, const int* __restrict__ list_t,
    float* __restrict__ contrib, float* __restrict__ out, int atomicMode){
  const int KT = INTER / 64;                 // 12 k-tiles
  int owner = blockIdx.x;                    // 1024 = 16 n-tiles x 64 experts
  int hi = owner >> 3;
  int e  = (owner & 7) + ((hi >> 4) << 3);   // all 16 n-blocks of an expert on one XCD
  int n0 = (hi & 15) * 128;
  int beg = offs[e], n_e = offs[e + 1] - beg;
  if (n_e <= 0) return;
  int tid = threadIdx.x, lane = tid & 63, wid = tid >> 6;
  int wm = wid & 3, wn = wid >> 2;           // 48-row m-quarter, 64-col n-half

  __shared__ unsigned short lB[3][128 * 64]; // 3 x 16 KB = 48 KB

  int bh = tid & 127, bg = tid >> 7;
  int hswz = (bh & 7) << 4;
  const float* dBase = wd + (size_t)e * INTER * HID + n0 + bh;

#define DN_ISSUE_B(t, rb_) { \
    const float* _p = dBase + (size_t)((t) * 64 + bg * 8) * HID; \
    _Pragma("unroll") for (int j = 0; j < 8; ++j){ \
      rb_[j] = _p[(size_t)j * HID]; rb_[8 + j] = _p[(size_t)(j + 32) * HID]; } }

#define DN_WRITE_B(buf, rb_) { \
    uint4 _p; \
    _p.x = f2bf(rb_[0]) | ((unsigned)f2bf(rb_[1]) << 16); \
    _p.y = f2bf(rb_[2]) | ((unsigned)f2bf(rb_[3]) << 16); \
    _p.z = f2bf(rb_[4]) | ((unsigned)f2bf(rb_[5]) << 16); \
    _p.w = f2bf(rb_[6]) | ((unsigned)f2bf(rb_[7]) << 16); \
    *(uint4*)((char*)&lB[buf][0] + bh * 128 + ((bg * 16) ^ hswz)) = _p; \
    _p.x = f2bf(rb_[8])  | ((unsigned)f2bf(rb_[9])  << 16); \
    _p.y = f2bf(rb_[10]) | ((unsigned)f2bf(rb_[11]) << 16); \
    _p.z = f2bf(rb_[12]) | ((unsigned)f2bf(rb_[13]) << 16); \
    _p.w = f2bf(rb_[14]) | ((unsigned)f2bf(rb_[15]) << 16); \
    *(uint4*)((char*)&lB[buf][0] + bh * 128 + ((bg * 16 + 64) ^ hswz)) = _p; }

#define DN_ISSUE_A(t, ra_) { \
    int _kk = (t) * 64 + ((lane >> 4) << 3); \
    _Pragma("unroll") for (int mf = 0; mf < 3; ++mf){ \
      const unsigned short* _ap = act + (size_t)aslot[mf] * INTER + _kk; \
      ra_[mf][0] = *(const short8*)_ap; \
      ra_[mf][1] = *(const short8*)(_ap + 32); } }

#define DN_MFMA(buf, ra_) { \
    _Pragma("unroll") for (int ks = 0; ks < 2; ++ks){ \
      short8 _bf[4]; \
      _Pragma("unroll") for (int nf = 0; nf < 4; ++nf){ \
        int _il = wn * 64 + nf * 16 + (lane & 15); \
        int _kb = (ks * 64 + ((lane >> 4) << 4)) ^ ((_il & 7) << 4); \
        _bf[nf] = *(const short8*)((const char*)&lB[buf][0] + _il * 128 + _kb); } \
      _Pragma("unroll") for (int mf = 0; mf < 3; ++mf) \
        _Pragma("unroll") for (int nf = 0; nf < 4; ++nf) \
          acc[mf][nf] = __builtin_amdgcn_mfma_f32_16x16x32_bf16(ra_[mf][ks], _bf[nf], acc[mf][nf], 0, 0, 0); } }

#define DN_BODY(T, ACUR, ANXT, SI, SW, LR, LW, DO_A, DO_B, DO_W) { \
    if (DO_A) DN_ISSUE_A((T) + 1, rA[ANXT]); \
    if (DO_B) DN_ISSUE_B((T) + 4, rb[SI]); \
    DN_MFMA(LR, rA[ACUR]); \
    if (DO_W) DN_WRITE_B(LW, rb[SW]); \
    BARRIER(); }

  for (int m0 = 0; m0 < n_e; m0 += 192){
    int aslot[3];
    #pragma unroll
    for (int mf = 0; mf < 3; ++mf){
      int r = wm * 48 + mf * 16 + (lane & 15);
      aslot[mf] = (m0 + r < n_e) ? (beg + m0 + r) : beg;
    }
    float rb[3][16];
    short8 rA[2][3][2];
    f32x4 acc[3][4] = {};

    DN_ISSUE_B(0, rb[0]);
    DN_ISSUE_B(1, rb[1]);
    DN_ISSUE_B(2, rb[2]);
    DN_ISSUE_A(0, rA[0]);
    DN_WRITE_B(0, rb[0]);
    DN_WRITE_B(1, rb[1]);
    DN_ISSUE_B(3, rb[0]);
    BARRIER();

    DN_BODY(0,  0, 1, 1, 2, 0, 2, 1, 1, 1);
    DN_BODY(1,  1, 0, 2, 0, 1, 0, 1, 1, 1);
    DN_BODY(2,  0, 1, 0, 1, 2, 1, 1, 1, 1);
    DN_BODY(3,  1, 0, 1, 2, 0, 2, 1, 1, 1);
    DN_BODY(4,  0, 1, 2, 0, 1, 0, 1, 1, 1);
    DN_BODY(5,  1, 0, 0, 1, 2, 1, 1, 1, 1);
    DN_BODY(6,  0, 1, 1, 2, 0, 2, 1, 1, 1);
    DN_BODY(7,  1, 0, 2, 0, 1, 0, 1, 1, 1);   // issues B11 (last)
    DN_BODY(8,  0, 1, 0, 1, 2, 1, 1, 0, 1);
    DN_BODY(9,  1, 0, 1, 2, 0, 2, 1, 0, 1);   // writes B11 (last)
    DN_BODY(10, 0, 1, 2, 0, 1, 0, 1, 0, 0);
    DN_BODY(11, 1, 0, 0, 1, 2, 1, 0, 0, 0);

    #pragma unroll
    for (int mf = 0; mf < 3; ++mf){
      #pragma unroll
      for (int rr = 0; rr < 4; ++rr){
        int r = wm * 48 + mf * 16 + ((lane >> 4) << 2) + rr;
        if (m0 + r < n_e){
          int slot = beg + m0 + r;
          #pragma unroll
          for (int nf = 0; nf < 4; ++nf){
            float v = acc[mf][nf][rr];
            int h = n0 + wn * 64 + nf * 16 + (lane & 15);
            if (atomicMode) atomicAdd(&out[(size_t)list_t[slot] * HID + h], v);
            else            contrib[(size_t)slot * HID + h] = v;
          }
        }
      }
    }
  }
}

// ---------------- kernel 7: deterministic 8-way combine ----------------
__global__ void k_reduce(const float* __restrict__ contrib, const int* __restrict__ slot_of,
                         float* __restrict__ out){
  int bx = blockIdx.x;
  int t = bx >> 1, seg = bx & 1, tid = threadIdx.x;
  __shared__ int ss[TOPK];
  if (tid < TOPK) ss[tid] = slot_of[t * TOPK + tid];
  __syncthreads();
  int h = (seg * 256 + tid) * 4;
  f32x4 s = {0.f, 0.f, 0.f, 0.f};
  #pragma unroll
  for (int k = 0; k < TOPK; ++k){
    f32x4 v = *(const f32x4*)(contrib + (size_t)ss[k] * HID + h);
    s += v;
  }
  *(f32x4*)(out + (size_t)t * HID + h) = s;
}

extern "C" void kernel_launch(void* const* d_in, const int* in_sizes, int n_in,
                              void* d_out, int out_size, void* d_ws, size_t ws_size,
                              hipStream_t stream){
  const float* x   = (const float*)d_in[0];
  const float* gw  = (const float*)d_in[1];
  const float* wgp = (const float*)d_in[2];
  const float* wup = (const float*)d_in[3];
  const float* wdp = (const float*)d_in[4];
  float* out = (float*)d_out;
  char* ws = (char*)d_ws;

  int*   top_idx = (int*)  (ws + 0);
  float* top_w   = (float*)(ws + 32768);
  int*   offs    = (int*)  (ws + 65536);
  int*   list_t  = (int*)  (ws + 69632);
  float* list_w  = (float*)(ws + 102400);
  int*   slot_of = (int*)  (ws + 135168);
  unsigned short* xbf = (unsigned short*)(ws + 167936);             // 4 MB
  unsigned short* act = (unsigned short*)(ws + 167936 + 4194304);   // 12 MB
  float* contrib = (float*)(ws + 167936 + 4194304 + 12582912);      // 64 MB
  size_t need_full = (size_t)167936 + 4194304 + 12582912 + 67108864;
  int atomicMode = (ws_size < need_full) ? 1 : 0;

  k_convert_x<<<1024, 256, 0, stream>>>(x, xbf);
  k_router   <<<1024, 256, 0, stream>>>(x, gw, top_idx, top_w);
  k_hist     <<<1,    256, 0, stream>>>(top_idx, offs);
  k_compact  <<<64,   256, 0, stream>>>(top_idx, top_w, offs, list_t, list_w, slot_of);
  k_gateup   <<<dim3(12 * NEXP), 512, 0, stream>>>(xbf, wgp, wup, offs, list_t, list_w, act);
  if (atomicMode){
    hipMemsetAsync(d_out, 0, (size_t)out_size * sizeof(float), stream);
    k_down  <<<dim3(16 * NEXP), 512, 0, stream>>>(act, wdp, offs, list_t, contrib, out, 1);
  } else {
    k_down  <<<dim3(16 * NEXP), 512, 0, stream>>>(act, wdp, offs, list_t, contrib, out, 0);
    k_reduce<<<2048, 256, 0, stream>>>(contrib, slot_of, out);
  }
}

// Round 4
// 541.284 us; speedup vs baseline: 1.3587x; 1.3587x over previous
//
#include <hip/hip_runtime.h>
#include <cstdint>

#define T_TOK 1024
#define HID   2048
#define NEXP  64
#define TOPK  8
#define INTER 768

typedef __attribute__((ext_vector_type(8))) short short8;   // 8 x bf16 (4 VGPRs)
typedef __attribute__((ext_vector_type(4))) float f32x4;

__device__ __forceinline__ unsigned short f2bf(float f){
  unsigned u = __float_as_uint(f);
  u += 0x7FFFu + ((u >> 16) & 1u);   // RNE; inputs are finite
  return (unsigned short)(u >> 16);
}

// ---------------- kernel 1: x (fp32) -> bf16 once per launch ----------------
__global__ void k_convert_x(const float* __restrict__ x, unsigned short* __restrict__ xbf){
  int gid = blockIdx.x * 256 + threadIdx.x;
  const float4* src = (const float4*)(x + (size_t)gid * 8);
  float4 a = src[0], b = src[1];
  uint4 p;
  p.x = f2bf(a.x) | ((unsigned)f2bf(a.y) << 16);
  p.y = f2bf(a.z) | ((unsigned)f2bf(a.w) << 16);
  p.z = f2bf(b.x) | ((unsigned)f2bf(b.y) << 16);
  p.w = f2bf(b.z) | ((unsigned)f2bf(b.w) << 16);
  *(uint4*)(xbf + (size_t)gid * 8) = p;
}

// ---------------- kernel 2: router (fp32-exact logits, top-8) ----------------
__global__ void k_router(const float* __restrict__ x, const float* __restrict__ gw,
                         int* __restrict__ top_idx, float* __restrict__ top_w){
  int t = blockIdx.x;
  int tid = threadIdx.x;
  __shared__ float  xs[HID];
  __shared__ double part[4][NEXP];
  for (int i = tid; i < HID; i += 256) xs[i] = x[(size_t)t * HID + i];
  __syncthreads();
  int e = tid & 63, q = tid >> 6;
  double acc = 0.0;
  const float* gp = gw + e;
  #pragma unroll 8
  for (int h = q * 512; h < q * 512 + 512; ++h)
    acc += (double)xs[h] * (double)gp[(size_t)h * NEXP];
  part[q][e] = acc;
  __syncthreads();
  if (tid < 64){
    float logit = (float)(part[0][e] + part[1][e] + part[2][e] + part[3][e]);
    float cur = logit;
    float vals[TOPK]; int idxs[TOPK];
    #pragma unroll
    for (int k = 0; k < TOPK; ++k){
      float m = cur; int mi = e;
      #pragma unroll
      for (int off = 32; off > 0; off >>= 1){
        float ov = __shfl_xor(m, off);
        int   oi = __shfl_xor(mi, off);
        if (ov > m || (ov == m && oi < mi)){ m = ov; mi = oi; }
      }
      vals[k] = m; idxs[k] = mi;
      if (e == mi) cur = -1e30f;
    }
    float mx = vals[0], s = 0.f, ev[TOPK];
    #pragma unroll
    for (int k = 0; k < TOPK; ++k){ ev[k] = expf(vals[k] - mx); s += ev[k]; }
    #pragma unroll
    for (int k = 0; k < TOPK; ++k)
      if (e == k){ top_idx[t * TOPK + k] = idxs[k]; top_w[t * TOPK + k] = ev[k] / s; }
  }
}

// ---------------- kernel 3: per-expert histogram + exclusive scan ----------------
__global__ void k_hist(const int* __restrict__ top_idx, int* __restrict__ offs){
  __shared__ int hist[NEXP];
  int tid = threadIdx.x;
  if (tid < NEXP) hist[tid] = 0;
  __syncthreads();
  for (int j = tid; j < T_TOK * TOPK; j += 256) atomicAdd(&hist[top_idx[j]], 1);
  __syncthreads();
  if (tid == 0){
    int run = 0;
    for (int e = 0; e < NEXP; ++e){ offs[e] = run; run += hist[e]; }
    offs[NEXP] = run;
  }
}

// ---------------- kernel 4: deterministic ordered compaction ----------------
__global__ void k_compact(const int* __restrict__ top_idx, const float* __restrict__ top_w,
                          const int* __restrict__ offs, int* __restrict__ list_t,
                          float* __restrict__ list_w, int* __restrict__ slot_of){
  int e = blockIdx.x, tid = threadIdx.x;
  __shared__ int sc[256];
  int j0 = tid * 32, cnt = 0;
  for (int jj = 0; jj < 32; ++jj) cnt += (top_idx[j0 + jj] == e);
  sc[tid] = cnt; __syncthreads();
  for (int d = 1; d < 256; d <<= 1){
    int v = (tid >= d) ? sc[tid - d] : 0;
    __syncthreads();
    sc[tid] += v;
    __syncthreads();
  }
  int pos = offs[e] + sc[tid] - cnt;
  for (int jj = 0; jj < 32; ++jj){
    int j = j0 + jj;
    if (top_idx[j] == e){
      list_t[pos]  = j >> 3;
      list_w[pos]  = top_w[j];
      slot_of[j]   = pos;
      ++pos;
    }
  }
}

#define GLL16(SRC, DST) \
  __builtin_amdgcn_global_load_lds((const __attribute__((address_space(1))) unsigned int*)(SRC), \
                                   (__attribute__((address_space(3))) unsigned int*)(DST), 16, 0, 0)

#define WAITV(N) do { asm volatile("s_waitcnt vmcnt(" #N ")" ::: "memory"); \
                      __builtin_amdgcn_s_barrier(); } while (0)

// ---------------- kernel 5: gate/up GEMM + SwiGLU ----------------
// BM=192 (whole expert), BN=64 x {gate,up}, BK=64, KT=32. 512 thr = 8 waves (4m x 2n).
// B: fp32 staged via global_load_lds into a 4-deep LDS ring (no VGPR cost); bf16
// conversion at fragment build. Counted vmcnt(4): B(t+3) never drains in main loop.
// A: bf16 fragments straight from global (L3-resident xbf), 2-set rotation.
__global__ __launch_bounds__(512) void k_gateup(
    const unsigned short* __restrict__ xbf, const float* __restrict__ wg,
    const float* __restrict__ wu, const int* __restrict__ offs,
    const int* __restrict__ list_t, const float* __restrict__ list_w,
    unsigned short* __restrict__ act){
  int e  = blockIdx.y;
  int i0 = blockIdx.x * 64;
  int beg = offs[e], n_e = offs[e + 1] - beg;
  if (n_e <= 0) return;
  int tid = threadIdx.x, lane = tid & 63, wid = tid >> 6;
  int wm = wid & 3, wn = wid >> 2;           // 48-row m-quarter, 32-col n-half

  __shared__ float lB[4][2][64 * 64];        // 4 bufs x 2 mats x 16KB = 128 KB
  __shared__ int   sTok[192];
  __shared__ float sWgt[192];

  const float* gBase = wg + (size_t)e * HID * INTER + i0;
  const float* uBase = wu + (size_t)e * HID * INTER + i0;

// stage tile T into buf T&3: 32 dwordx4 wave-insts, 4 per wave (= 4 vmcnt/thread).
// source col-group pre-swizzled by s=(q16>>1)&1 (== (k>>3)&1) XOR bit2 -> read side
// applies same XOR => bank-conflict-free (2-way) frag reads. LDS dest stays linear.
#define GU_STAGE(T) { \
    float* _base = &lB[(T) & 3][0][0]; \
    _Pragma("unroll") for (int jj = 0; jj < 4; ++jj){ \
      int _idx = wid * 4 + jj;               /* 0..31 */ \
      int _mat = _idx >> 4, _q16 = _idx & 15; \
      int _s = (_q16 >> 1) & 1; \
      int _row = (T) * 64 + _q16 * 4 + (lane >> 4); \
      const float* _src = (_mat ? uBase : gBase) + (size_t)_row * INTER \
                          + (((lane & 15) ^ (_s << 2)) << 2); \
      float* _dst = _base + _mat * 4096 + _q16 * 256 + lane * 4; \
      GLL16(_src, _dst); } }

#define GU_ISSUE_A(T, ra_) { \
    int _kk = (T) * 64 + ((lane >> 4) << 3); \
    _Pragma("unroll") for (int mf = 0; mf < 3; ++mf){ \
      const unsigned short* _ap = xbf + (size_t)tokA[mf] * HID + _kk; \
      ra_[mf][0] = *(const short8*)_ap; \
      ra_[mf][1] = *(const short8*)(_ap + 32); } }

// frag build: 8 fp32 b32 reads + cvt per frag; addr = (k>>2)*1024 + (k&3)*256
//             + ((col>>2 ^ (kq&1)<<2)<<4) + (col&3)*4
#define GU_MFMA_PHASE(T, ra_) { \
    const char* _lg = (const char*)&lB[(T) & 3][0][0]; \
    const char* _lu = (const char*)&lB[(T) & 3][1][0]; \
    int _c = lane & 15, _kq = lane >> 4; \
    _Pragma("unroll") for (int ks = 0; ks < 2; ++ks){ \
      short8 _bg[2], _bu[2]; \
      _Pragma("unroll") for (int nf = 0; nf < 2; ++nf){ \
        int _col = wn * 32 + nf * 16 + _c; \
        int _off0 = ((((_col >> 2) ^ ((_kq & 1) << 2)) << 4) + ((_col & 3) << 2)); \
        union { uint4 u; short8 s; } _vg, _vu; \
        _Pragma("unroll") for (int jp = 0; jp < 4; ++jp){ \
          int _k0 = ks * 32 + _kq * 8 + jp * 2; \
          int _a0 = ((_k0 >> 2) << 10) + ((_k0 & 3) << 8) + _off0; \
          int _a1 = _a0 + 256; \
          float _g0 = *(const float*)(_lg + _a0), _g1 = *(const float*)(_lg + _a1); \
          float _u0 = *(const float*)(_lu + _a0), _u1 = *(const float*)(_lu + _a1); \
          ((unsigned*)&_vg)[jp] = f2bf(_g0) | ((unsigned)f2bf(_g1) << 16); \
          ((unsigned*)&_vu)[jp] = f2bf(_u0) | ((unsigned)f2bf(_u1) << 16); } \
        _bg[nf] = _vg.s; _bu[nf] = _vu.s; } \
      _Pragma("unroll") for (int mf = 0; mf < 3; ++mf) \
        _Pragma("unroll") for (int nf = 0; nf < 2; ++nf){ \
          accg[mf][nf] = __builtin_amdgcn_mfma_f32_16x16x32_bf16(ra_[mf][ks], _bg[nf], accg[mf][nf], 0, 0, 0); \
          accu[mf][nf] = __builtin_amdgcn_mfma_f32_16x16x32_bf16(ra_[mf][ks], _bu[nf], accu[mf][nf], 0, 0, 0); } } }

// body: issue A(t+1) (6 loads, BEFORE B so the pre-barrier wait retires it);
//       stage B(t+3) (4 loads); MFMA(t); vmcnt(4) leaves only B(t+3) in flight.
#define GU_BODY(T, RAc, RAn) { \
    GU_ISSUE_A((T) + 1, RAn); \
    GU_STAGE((T) + 3); \
    GU_MFMA_PHASE(T, RAc); \
    WAITV(4); }

  for (int m0 = 0; m0 < n_e; m0 += 192){
    __syncthreads();                      // protect prev iter's sWgt reads (rare path)
    if (tid < 192){
      int sl = beg + m0 + tid;
      if (m0 + tid < n_e){ sTok[tid] = list_t[sl]; sWgt[tid] = list_w[sl]; }
      else               { sTok[tid] = list_t[beg]; sWgt[tid] = 0.f; }
    }
    __syncthreads();
    int tokA[3];
    #pragma unroll
    for (int mf = 0; mf < 3; ++mf) tokA[mf] = sTok[wm * 48 + mf * 16 + (lane & 15)];

    short8 rA0[3][2], rA1[3][2];
    f32x4 accg[3][2] = {}; f32x4 accu[3][2] = {};

    // prologue: A(0) then B(0..2); retire A0+B0, keep B1,B2 in flight
    GU_ISSUE_A(0, rA0);
    GU_STAGE(0); GU_STAGE(1); GU_STAGE(2);
    WAITV(8);

    #pragma unroll 1
    for (int t = 0; t < 28; t += 2){
      GU_BODY(t,     rA0, rA1);
      GU_BODY(t + 1, rA1, rA0);
    }
    GU_BODY(28, rA0, rA1);                           // stages B(31)
    { GU_ISSUE_A(30, rA0); GU_MFMA_PHASE(29, rA1); WAITV(0); }
    { GU_ISSUE_A(31, rA1); GU_MFMA_PHASE(30, rA0); WAITV(0); }
    GU_MFMA_PHASE(31, rA1);

    // epilogue: SwiGLU * routing weight -> bf16
    #pragma unroll
    for (int mf = 0; mf < 3; ++mf){
      #pragma unroll
      for (int rr = 0; rr < 4; ++rr){
        int r = wm * 48 + mf * 16 + ((lane >> 4) << 2) + rr;
        if (m0 + r < n_e){
          int slot = beg + m0 + r;
          float wgt = sWgt[r];
          #pragma unroll
          for (int nf = 0; nf < 2; ++nf){
            float g = accg[mf][nf][rr], u = accu[mf][nf][rr];
            float h = (g / (1.f + expf(-g))) * u * wgt;
            act[(size_t)slot * INTER + i0 + wn * 32 + nf * 16 + (lane & 15)] = f2bf(h);
          }
        }
      }
    }
  }
}

// ---------------- kernel 6: down-proj GEMM ----------------
// BM=192, BN=128, BK=64, KT=12. Same ring pipeline; B tile = 64k x 128col fp32 (32KB).
__global__ __launch_bounds__(512) void k_down(
    const unsigned short* __restrict__ act, const float* __restrict__ wd,
    const int* __restrict__ offs, const int* __restrict__ list_t,
    float* __restrict__ contrib, float* __restrict__ out, int atomicMode){
  int e  = blockIdx.y;
  int n0 = blockIdx.x * 128;
  int beg = offs[e], n_e = offs[e + 1] - beg;
  if (n_e <= 0) return;
  int tid = threadIdx.x, lane = tid & 63, wid = tid >> 6;
  int wm = wid & 3, wn = wid >> 2;           // 48-row m-quarter, 64-col n-half

  __shared__ float lB[4][64 * 128];          // 4 x 32KB = 128 KB
  __shared__ int   sTok[192];

  const float* dBase = wd + (size_t)e * INTER * HID + n0;

#define DN_STAGE(T) { \
    float* _base = &lB[(T) & 3][0]; \
    _Pragma("unroll") for (int jj = 0; jj < 4; ++jj){ \
      int _idx = wid * 4 + jj;               /* 0..31, rows 2*_idx..+1 */ \
      int _s = (_idx >> 2) & 1; \
      int _row = (T) * 64 + _idx * 2 + (lane >> 5); \
      const float* _src = dBase + (size_t)_row * HID + (((lane & 31) ^ (_s << 2)) << 2); \
      float* _dst = _base + _idx * 256 + lane * 4; \
      GLL16(_src, _dst); } }

#define DN_ISSUE_A(T, ra_) { \
    int _kk = (T) * 64 + ((lane >> 4) << 3); \
    _Pragma("unroll") for (int mf = 0; mf < 3; ++mf){ \
      const unsigned short* _ap = act + (size_t)aslot[mf] * INTER + _kk; \
      ra_[mf][0] = *(const short8*)_ap; \
      ra_[mf][1] = *(const short8*)(_ap + 32); } }

// addr = (k>>1)*1024 + (k&1)*512 + ((col>>2 ^ (kq&1)<<2)<<4) + (col&3)*4
#define DN_MFMA_PHASE(T, ra_) { \
    const char* _lb = (const char*)&lB[(T) & 3][0]; \
    int _c = lane & 15, _kq = lane >> 4; \
    _Pragma("unroll") for (int ks = 0; ks < 2; ++ks){ \
      short8 _bf[4]; \
      _Pragma("unroll") for (int nf = 0; nf < 4; ++nf){ \
        int _col = wn * 64 + nf * 16 + _c; \
        int _off0 = ((((_col >> 2) ^ ((_kq & 1) << 2)) << 4) + ((_col & 3) << 2)); \
        union { uint4 u; short8 s; } _vb; \
        _Pragma("unroll") for (int jp = 0; jp < 4; ++jp){ \
          int _kh = ks * 16 + _kq * 4 + jp;   /* k>>1 */ \
          int _a0 = (_kh << 10) + _off0; \
          float _b0 = *(const float*)(_lb + _a0); \
          float _b1 = *(const float*)(_lb + _a0 + 512); \
          ((unsigned*)&_vb)[jp] = f2bf(_b0) | ((unsigned)f2bf(_b1) << 16); } \
        _bf[nf] = _vb.s; } \
      _Pragma("unroll") for (int mf = 0; mf < 3; ++mf) \
        _Pragma("unroll") for (int nf = 0; nf < 4; ++nf) \
          acc[mf][nf] = __builtin_amdgcn_mfma_f32_16x16x32_bf16(ra_[mf][ks], _bf[nf], acc[mf][nf], 0, 0, 0); } }

#define DN_BODY(T, RAc, RAn) { \
    DN_ISSUE_A((T) + 1, RAn); \
    DN_STAGE((T) + 3); \
    DN_MFMA_PHASE(T, RAc); \
    WAITV(4); }

  for (int m0 = 0; m0 < n_e; m0 += 192){
    __syncthreads();
    if (tid < 192){
      int sl = beg + m0 + tid;
      sTok[tid] = (m0 + tid < n_e) ? list_t[sl] : 0;
    }
    __syncthreads();
    int aslot[3];
    #pragma unroll
    for (int mf = 0; mf < 3; ++mf){
      int r = wm * 48 + mf * 16 + (lane & 15);
      aslot[mf] = (m0 + r < n_e) ? (beg + m0 + r) : beg;
    }
    short8 rA0[3][2], rA1[3][2];
    f32x4 acc[3][4] = {};

    DN_ISSUE_A(0, rA0);
    DN_STAGE(0); DN_STAGE(1); DN_STAGE(2);
    WAITV(8);

    #pragma unroll 1
    for (int t = 0; t < 8; t += 2){
      DN_BODY(t,     rA0, rA1);
      DN_BODY(t + 1, rA1, rA0);
    }
    DN_BODY(8, rA0, rA1);                            // stages B(11)
    { DN_ISSUE_A(10, rA0); DN_MFMA_PHASE(9,  rA1); WAITV(0); }
    { DN_ISSUE_A(11, rA1); DN_MFMA_PHASE(10, rA0); WAITV(0); }
    DN_MFMA_PHASE(11, rA1);

    #pragma unroll
    for (int mf = 0; mf < 3; ++mf){
      #pragma unroll
      for (int rr = 0; rr < 4; ++rr){
        int r = wm * 48 + mf * 16 + ((lane >> 4) << 2) + rr;
        if (m0 + r < n_e){
          int slot = beg + m0 + r;
          #pragma unroll
          for (int nf = 0; nf < 4; ++nf){
            float v = acc[mf][nf][rr];
            int h = n0 + wn * 64 + nf * 16 + (lane & 15);
            if (atomicMode) atomicAdd(&out[(size_t)sTok[r] * HID + h], v);
            else            contrib[(size_t)slot * HID + h] = v;
          }
        }
      }
    }
  }
}

// ---------------- kernel 7: deterministic 8-way combine ----------------
__global__ void k_reduce(const float* __restrict__ contrib, const int* __restrict__ slot_of,
                         float* __restrict__ out){
  int bx = blockIdx.x;
  int t = bx >> 1, seg = bx & 1, tid = threadIdx.x;
  __shared__ int ss[TOPK];
  if (tid < TOPK) ss[tid] = slot_of[t * TOPK + tid];
  __syncthreads();
  int h = (seg * 256 + tid) * 4;
  f32x4 s = {0.f, 0.f, 0.f, 0.f};
  #pragma unroll
  for (int k = 0; k < TOPK; ++k){
    f32x4 v = *(const f32x4*)(contrib + (size_t)ss[k] * HID + h);
    s += v;
  }
  *(f32x4*)(out + (size_t)t * HID + h) = s;
}

extern "C" void kernel_launch(void* const* d_in, const int* in_sizes, int n_in,
                              void* d_out, int out_size, void* d_ws, size_t ws_size,
                              hipStream_t stream){
  const float* x   = (const float*)d_in[0];
  const float* gw  = (const float*)d_in[1];
  const float* wgp = (const float*)d_in[2];
  const float* wup = (const float*)d_in[3];
  const float* wdp = (const float*)d_in[4];
  float* out = (float*)d_out;
  char* ws = (char*)d_ws;

  int*   top_idx = (int*)  (ws + 0);
  float* top_w   = (float*)(ws + 32768);
  int*   offs    = (int*)  (ws + 65536);
  int*   list_t  = (int*)  (ws + 69632);
  float* list_w  = (float*)(ws + 102400);
  int*   slot_of = (int*)  (ws + 135168);
  unsigned short* xbf = (unsigned short*)(ws + 167936);             // 4 MB
  unsigned short* act = (unsigned short*)(ws + 167936 + 4194304);   // 12 MB
  float* contrib = (float*)(ws + 167936 + 4194304 + 12582912);      // 64 MB
  size_t need_full = (size_t)167936 + 4194304 + 12582912 + 67108864;
  int atomicMode = (ws_size < need_full) ? 1 : 0;

  k_convert_x<<<1024, 256, 0, stream>>>(x, xbf);
  k_router   <<<1024, 256, 0, stream>>>(x, gw, top_idx, top_w);
  k_hist     <<<1,    256, 0, stream>>>(top_idx, offs);
  k_compact  <<<64,   256, 0, stream>>>(top_idx, top_w, offs, list_t, list_w, slot_of);
  k_gateup   <<<dim3(INTER / 64, NEXP), 512, 0, stream>>>(xbf, wgp, wup, offs, list_t, list_w, act);
  if (atomicMode){
    hipMemsetAsync(d_out, 0, (size_t)out_size * sizeof(float), stream);
    k_down  <<<dim3(HID / 128, NEXP), 512, 0, stream>>>(act, wdp, offs, list_t, contrib, out, 1);
  } else {
    k_down  <<<dim3(HID / 128, NEXP), 512, 0, stream>>>(act, wdp, offs, list_t, contrib, out, 0);
    k_reduce<<<2048, 256, 0, stream>>>(contrib, slot_of, out);
  }
}

// Round 5
// 421.143 us; speedup vs baseline: 1.7463x; 1.2853x over previous
//
#include <hip/hip_runtime.h>
#include <cstdint>

#define T_TOK 1024
#define HID   2048
#define NEXP  64
#define TOPK  8
#define INTER 768

typedef __attribute__((ext_vector_type(8))) short short8;   // 8 x bf16 (4 VGPRs)
typedef __attribute__((ext_vector_type(4))) float f32x4;

__device__ __forceinline__ unsigned short f2bf(float f){
  unsigned u = __float_as_uint(f);
  u += 0x7FFFu + ((u >> 16) & 1u);   // RNE; inputs are finite
  return (unsigned short)(u >> 16);
}

// ---------------- kernel 1: x (fp32) -> bf16 once per launch ----------------
__global__ void k_convert_x(const float* __restrict__ x, unsigned short* __restrict__ xbf){
  int gid = blockIdx.x * 256 + threadIdx.x;
  const float4* src = (const float4*)(x + (size_t)gid * 8);
  float4 a = src[0], b = src[1];
  uint4 p;
  p.x = f2bf(a.x) | ((unsigned)f2bf(a.y) << 16);
  p.y = f2bf(a.z) | ((unsigned)f2bf(a.w) << 16);
  p.z = f2bf(b.x) | ((unsigned)f2bf(b.y) << 16);
  p.w = f2bf(b.z) | ((unsigned)f2bf(b.w) << 16);
  *(uint4*)(xbf + (size_t)gid * 8) = p;
}

// ---------------- kernel 2: router (fp32-exact logits, top-8) ----------------
__global__ void k_router(const float* __restrict__ x, const float* __restrict__ gw,
                         int* __restrict__ top_idx, float* __restrict__ top_w){
  int t = blockIdx.x;
  int tid = threadIdx.x;
  __shared__ float  xs[HID];
  __shared__ double part[4][NEXP];
  for (int i = tid; i < HID; i += 256) xs[i] = x[(size_t)t * HID + i];
  __syncthreads();
  int e = tid & 63, q = tid >> 6;
  double acc = 0.0;
  const float* gp = gw + e;
  #pragma unroll 8
  for (int h = q * 512; h < q * 512 + 512; ++h)
    acc += (double)xs[h] * (double)gp[(size_t)h * NEXP];
  part[q][e] = acc;
  __syncthreads();
  if (tid < 64){
    float logit = (float)(part[0][e] + part[1][e] + part[2][e] + part[3][e]);
    float cur = logit;
    float vals[TOPK]; int idxs[TOPK];
    #pragma unroll
    for (int k = 0; k < TOPK; ++k){
      float m = cur; int mi = e;
      #pragma unroll
      for (int off = 32; off > 0; off >>= 1){
        float ov = __shfl_xor(m, off);
        int   oi = __shfl_xor(mi, off);
        if (ov > m || (ov == m && oi < mi)){ m = ov; mi = oi; }
      }
      vals[k] = m; idxs[k] = mi;
      if (e == mi) cur = -1e30f;
    }
    float mx = vals[0], s = 0.f, ev[TOPK];
    #pragma unroll
    for (int k = 0; k < TOPK; ++k){ ev[k] = expf(vals[k] - mx); s += ev[k]; }
    #pragma unroll
    for (int k = 0; k < TOPK; ++k)
      if (e == k){ top_idx[t * TOPK + k] = idxs[k]; top_w[t * TOPK + k] = ev[k] / s; }
  }
}

// ---------------- kernel 3: per-expert histogram + exclusive scan ----------------
__global__ void k_hist(const int* __restrict__ top_idx, int* __restrict__ offs){
  __shared__ int hist[NEXP];
  int tid = threadIdx.x;
  if (tid < NEXP) hist[tid] = 0;
  __syncthreads();
  for (int j = tid; j < T_TOK * TOPK; j += 256) atomicAdd(&hist[top_idx[j]], 1);
  __syncthreads();
  if (tid == 0){
    int run = 0;
    for (int e = 0; e < NEXP; ++e){ offs[e] = run; run += hist[e]; }
    offs[NEXP] = run;
  }
}

// ---------------- kernel 4: deterministic ordered compaction ----------------
__global__ void k_compact(const int* __restrict__ top_idx, const float* __restrict__ top_w,
                          const int* __restrict__ offs, int* __restrict__ list_t,
                          float* __restrict__ list_w, int* __restrict__ slot_of){
  int e = blockIdx.x, tid = threadIdx.x;
  __shared__ int sc[256];
  int j0 = tid * 32, cnt = 0;
  for (int jj = 0; jj < 32; ++jj) cnt += (top_idx[j0 + jj] == e);
  sc[tid] = cnt; __syncthreads();
  for (int d = 1; d < 256; d <<= 1){
    int v = (tid >= d) ? sc[tid - d] : 0;
    __syncthreads();
    sc[tid] += v;
    __syncthreads();
  }
  int pos = offs[e] + sc[tid] - cnt;
  for (int jj = 0; jj < 32; ++jj){
    int j = j0 + jj;
    if (top_idx[j] == e){
      list_t[pos]  = j >> 3;
      list_w[pos]  = top_w[j];
      slot_of[j]   = pos;
      ++pos;
    }
  }
}

#define BARRIER() do { asm volatile("s_waitcnt lgkmcnt(0)" ::: "memory"); \
                       __builtin_amdgcn_s_barrier(); } while (0)

// ---------------- kernel 5: gate/up GEMM + SwiGLU ----------------
// 256 thr = 4 waves, each wave owns 48 rows (BM=192 = whole expert).
// BN=32 x {gate,up}, BK=64, KT=32. bf16 LDS (16 KB dbuf), ds_read_b128 frags.
// Small block => 3+ co-resident blocks/CU for TLP latency hiding.
__global__ __launch_bounds__(256) void k_gateup(
    const unsigned short* __restrict__ xbf, const float* __restrict__ wg,
    const float* __restrict__ wu, const int* __restrict__ offs,
    const int* __restrict__ list_t, const float* __restrict__ list_w,
    unsigned short* __restrict__ act){
  int e  = blockIdx.y;
  int i0 = blockIdx.x * 32;
  int beg = offs[e], n_e = offs[e + 1] - beg;
  if (n_e <= 0) return;
  int tid = threadIdx.x, lane = tid & 63, wid = tid >> 6;
  int cLane = lane & 15, kqB = (lane >> 4) << 4;

  __shared__ unsigned short lB[2][2][32 * 64];   // [buf][mat][col*64+k], 16 KB
  __shared__ int   sTok[192];
  __shared__ float sWgt[192];
  char* ldsBase = (char*)&lB[0][0][0];

  int colB = tid & 31, kg = tid >> 5;            // stage: col, k-group (8 rows)
  int wOff = (kg << 4) ^ ((colB & 7) << 4);
  const float* gBase = wg + (size_t)e * HID * INTER + i0 + colB;
  const float* uBase = wu + (size_t)e * HID * INTER + i0 + colB;

#define GU_ISSUE_B(T, rg_, ru_) { \
    const float* _gp = gBase + (size_t)((T) * 64 + kg * 8) * INTER; \
    const float* _up = uBase + (size_t)((T) * 64 + kg * 8) * INTER; \
    _Pragma("unroll") for (int j = 0; j < 8; ++j){ \
      rg_[j] = _gp[(size_t)j * INTER]; ru_[j] = _up[(size_t)j * INTER]; } }

#define GU_WRITE_B(BUF, rg_, ru_) { \
    uint4 _p; \
    _p.x = f2bf(rg_[0]) | ((unsigned)f2bf(rg_[1]) << 16); \
    _p.y = f2bf(rg_[2]) | ((unsigned)f2bf(rg_[3]) << 16); \
    _p.z = f2bf(rg_[4]) | ((unsigned)f2bf(rg_[5]) << 16); \
    _p.w = f2bf(rg_[6]) | ((unsigned)f2bf(rg_[7]) << 16); \
    *(uint4*)(ldsBase + (BUF) * 8192 + colB * 128 + wOff) = _p; \
    _p.x = f2bf(ru_[0]) | ((unsigned)f2bf(ru_[1]) << 16); \
    _p.y = f2bf(ru_[2]) | ((unsigned)f2bf(ru_[3]) << 16); \
    _p.z = f2bf(ru_[4]) | ((unsigned)f2bf(ru_[5]) << 16); \
    _p.w = f2bf(ru_[6]) | ((unsigned)f2bf(ru_[7]) << 16); \
    *(uint4*)(ldsBase + (BUF) * 8192 + 4096 + colB * 128 + wOff) = _p; }

#define GU_ISSUE_A(T, ra_) { \
    int _kk = (T) * 64 + ((lane >> 4) << 3); \
    _Pragma("unroll") for (int mf = 0; mf < 3; ++mf){ \
      const unsigned short* _ap = xbf + (size_t)tokA[mf] * HID + _kk; \
      ra_[mf][0] = *(const short8*)_ap; \
      ra_[mf][1] = *(const short8*)(_ap + 32); } }

#define GU_MFMA(BUF, ra_) { \
    _Pragma("unroll") for (int ks = 0; ks < 2; ++ks){ \
      short8 _bg[2], _bu[2]; \
      _Pragma("unroll") for (int nf = 0; nf < 2; ++nf){ \
        int _col = nf * 16 + cLane; \
        int _kb = (ks * 64 + kqB) ^ ((_col & 7) << 4); \
        _bg[nf] = *(const short8*)(ldsBase + (BUF) * 8192 + _col * 128 + _kb); \
        _bu[nf] = *(const short8*)(ldsBase + (BUF) * 8192 + 4096 + _col * 128 + _kb); } \
      _Pragma("unroll") for (int mf = 0; mf < 3; ++mf) \
        _Pragma("unroll") for (int nf = 0; nf < 2; ++nf){ \
          accg[mf][nf] = __builtin_amdgcn_mfma_f32_16x16x32_bf16(ra_[mf][ks], _bg[nf], accg[mf][nf], 0, 0, 0); \
          accu[mf][nf] = __builtin_amdgcn_mfma_f32_16x16x32_bf16(ra_[mf][ks], _bu[nf], accu[mf][nf], 0, 0, 0); } } }

  for (int m0 = 0; m0 < n_e; m0 += 192){
    __syncthreads();
    if (tid < 192){
      int sl = beg + m0 + tid;
      if (m0 + tid < n_e){ sTok[tid] = list_t[sl]; sWgt[tid] = list_w[sl]; }
      else               { sTok[tid] = list_t[beg]; sWgt[tid] = 0.f; }
    }
    __syncthreads();
    int tokA[3];
    #pragma unroll
    for (int mf = 0; mf < 3; ++mf) tokA[mf] = sTok[wid * 48 + mf * 16 + cLane];

    float sg0[8], su0[8], sg1[8], su1[8];
    short8 rA[3][2];
    f32x4 accg[3][2] = {}; f32x4 accu[3][2] = {};

    GU_ISSUE_B(0, sg0, su0);
    GU_ISSUE_B(1, sg1, su1);
    GU_WRITE_B(0, sg0, su0);
    BARRIER();
    #pragma unroll 1
    for (int t = 0; t < 32; t += 2){
      // even body: reads lds0(B(t)), issues B(t+2)->s0, writes s1=B(t+1)->lds1
      GU_ISSUE_A(t, rA);
      if (t + 2 < 32) GU_ISSUE_B(t + 2, sg0, su0);
      GU_MFMA(0, rA);
      GU_WRITE_B(1, sg1, su1);
      BARRIER();
      // odd body: reads lds1(B(t+1)), issues B(t+3)->s1, writes s0=B(t+2)->lds0
      GU_ISSUE_A(t + 1, rA);
      if (t + 3 < 32) GU_ISSUE_B(t + 3, sg1, su1);
      GU_MFMA(1, rA);
      if (t + 2 < 32) GU_WRITE_B(0, sg0, su0);
      BARRIER();
    }

    // epilogue: SwiGLU * routing weight -> bf16
    #pragma unroll
    for (int mf = 0; mf < 3; ++mf){
      #pragma unroll
      for (int rr = 0; rr < 4; ++rr){
        int r = wid * 48 + mf * 16 + ((lane >> 4) << 2) + rr;
        if (m0 + r < n_e){
          int slot = beg + m0 + r;
          float wgt = sWgt[r];
          #pragma unroll
          for (int nf = 0; nf < 2; ++nf){
            float g = accg[mf][nf][rr], u = accu[mf][nf][rr];
            float h = (g / (1.f + expf(-g))) * u * wgt;
            act[(size_t)slot * INTER + i0 + nf * 16 + cLane] = f2bf(h);
          }
        }
      }
    }
  }
}

// ---------------- kernel 6: down-proj GEMM ----------------
// 256 thr = 4 waves x 48 rows, BN=64, BK=64, KT=12. Same structure.
__global__ __launch_bounds__(256) void k_down(
    const unsigned short* __restrict__ act, const float* __restrict__ wd,
    const int* __restrict__ offs, const int* __restrict__ list_t,
    float* __restrict__ contrib, float* __restrict__ out, int atomicMode){
  int e  = blockIdx.y;
  int n0 = blockIdx.x * 64;
  int beg = offs[e], n_e = offs[e + 1] - beg;
  if (n_e <= 0) return;
  int tid = threadIdx.x, lane = tid & 63, wid = tid >> 6;
  int cLane = lane & 15, kqB = (lane >> 4) << 4;

  __shared__ unsigned short lB[2][64 * 64];      // [buf][col*64+k], 16 KB
  __shared__ int sTok[192];
  char* ldsBase = (char*)&lB[0][0];

  int colB = tid & 63, kg = tid >> 6;            // stage: col, k-group (16 rows)
  int wOff0 = ((kg << 5) + 0)  ^ ((colB & 7) << 4);
  int wOff1 = ((kg << 5) + 16) ^ ((colB & 7) << 4);
  const float* dBase = wd + (size_t)e * INTER * HID + n0 + colB;

#define DN_ISSUE_B(T, rb_) { \
    const float* _p = dBase + (size_t)((T) * 64 + kg * 16) * HID; \
    _Pragma("unroll") for (int j = 0; j < 16; ++j) rb_[j] = _p[(size_t)j * HID]; }

#define DN_WRITE_B(BUF, rb_) { \
    uint4 _p; \
    _p.x = f2bf(rb_[0]) | ((unsigned)f2bf(rb_[1]) << 16); \
    _p.y = f2bf(rb_[2]) | ((unsigned)f2bf(rb_[3]) << 16); \
    _p.z = f2bf(rb_[4]) | ((unsigned)f2bf(rb_[5]) << 16); \
    _p.w = f2bf(rb_[6]) | ((unsigned)f2bf(rb_[7]) << 16); \
    *(uint4*)(ldsBase + (BUF) * 8192 + colB * 128 + wOff0) = _p; \
    _p.x = f2bf(rb_[8])  | ((unsigned)f2bf(rb_[9])  << 16); \
    _p.y = f2bf(rb_[10]) | ((unsigned)f2bf(rb_[11]) << 16); \
    _p.z = f2bf(rb_[12]) | ((unsigned)f2bf(rb_[13]) << 16); \
    _p.w = f2bf(rb_[14]) | ((unsigned)f2bf(rb_[15]) << 16); \
    *(uint4*)(ldsBase + (BUF) * 8192 + colB * 128 + wOff1) = _p; }

#define DN_ISSUE_A(T, ra_) { \
    int _kk = (T) * 64 + ((lane >> 4) << 3); \
    _Pragma("unroll") for (int mf = 0; mf < 3; ++mf){ \
      const unsigned short* _ap = act + (size_t)aslot[mf] * INTER + _kk; \
      ra_[mf][0] = *(const short8*)_ap; \
      ra_[mf][1] = *(const short8*)(_ap + 32); } }

#define DN_MFMA(BUF, ra_) { \
    _Pragma("unroll") for (int ks = 0; ks < 2; ++ks){ \
      short8 _bf[4]; \
      _Pragma("unroll") for (int nf = 0; nf < 4; ++nf){ \
        int _col = nf * 16 + cLane; \
        int _kb = (ks * 64 + kqB) ^ ((_col & 7) << 4); \
        _bf[nf] = *(const short8*)(ldsBase + (BUF) * 8192 + _col * 128 + _kb); } \
      _Pragma("unroll") for (int mf = 0; mf < 3; ++mf) \
        _Pragma("unroll") for (int nf = 0; nf < 4; ++nf) \
          acc[mf][nf] = __builtin_amdgcn_mfma_f32_16x16x32_bf16(ra_[mf][ks], _bf[nf], acc[mf][nf], 0, 0, 0); } }

  for (int m0 = 0; m0 < n_e; m0 += 192){
    __syncthreads();
    if (tid < 192){
      int sl = beg + m0 + tid;
      sTok[tid] = (m0 + tid < n_e) ? list_t[sl] : 0;
    }
    __syncthreads();
    int aslot[3];
    #pragma unroll
    for (int mf = 0; mf < 3; ++mf){
      int r = wid * 48 + mf * 16 + cLane;
      aslot[mf] = (m0 + r < n_e) ? (beg + m0 + r) : beg;
    }
    float s0[16], s1[16];
    short8 rA[3][2];
    f32x4 acc[3][4] = {};

    DN_ISSUE_B(0, s0);
    DN_ISSUE_B(1, s1);
    DN_WRITE_B(0, s0);
    BARRIER();
    #pragma unroll 1
    for (int t = 0; t < 12; t += 2){
      DN_ISSUE_A(t, rA);
      if (t + 2 < 12) DN_ISSUE_B(t + 2, s0);
      DN_MFMA(0, rA);
      DN_WRITE_B(1, s1);
      BARRIER();
      DN_ISSUE_A(t + 1, rA);
      if (t + 3 < 12) DN_ISSUE_B(t + 3, s1);
      DN_MFMA(1, rA);
      if (t + 2 < 12) DN_WRITE_B(0, s0);
      BARRIER();
    }

    #pragma unroll
    for (int mf = 0; mf < 3; ++mf){
      #pragma unroll
      for (int rr = 0; rr < 4; ++rr){
        int r = wid * 48 + mf * 16 + ((lane >> 4) << 2) + rr;
        if (m0 + r < n_e){
          int slot = beg + m0 + r;
          #pragma unroll
          for (int nf = 0; nf < 4; ++nf){
            float v = acc[mf][nf][rr];
            int h = n0 + nf * 16 + cLane;
            if (atomicMode) atomicAdd(&out[(size_t)sTok[r] * HID + h], v);
            else            contrib[(size_t)slot * HID + h] = v;
          }
        }
      }
    }
  }
}

// ---------------- kernel 7: deterministic 8-way combine ----------------
__global__ void k_reduce(const float* __restrict__ contrib, const int* __restrict__ slot_of,
                         float* __restrict__ out){
  int bx = blockIdx.x;
  int t = bx >> 1, seg = bx & 1, tid = threadIdx.x;
  __shared__ int ss[TOPK];
  if (tid < TOPK) ss[tid] = slot_of[t * TOPK + tid];
  __syncthreads();
  int h = (seg * 256 + tid) * 4;
  f32x4 s = {0.f, 0.f, 0.f, 0.f};
  #pragma unroll
  for (int k = 0; k < TOPK; ++k){
    f32x4 v = *(const f32x4*)(contrib + (size_t)ss[k] * HID + h);
    s += v;
  }
  *(f32x4*)(out + (size_t)t * HID + h) = s;
}

extern "C" void kernel_launch(void* const* d_in, const int* in_sizes, int n_in,
                              void* d_out, int out_size, void* d_ws, size_t ws_size,
                              hipStream_t stream){
  const float* x   = (const float*)d_in[0];
  const float* gw  = (const float*)d_in[1];
  const float* wgp = (const float*)d_in[2];
  const float* wup = (const float*)d_in[3];
  const float* wdp = (const float*)d_in[4];
  float* out = (float*)d_out;
  char* ws = (char*)d_ws;

  int*   top_idx = (int*)  (ws + 0);
  float* top_w   = (float*)(ws + 32768);
  int*   offs    = (int*)  (ws + 65536);
  int*   list_t  = (int*)  (ws + 69632);
  float* list_w  = (float*)(ws + 102400);
  int*   slot_of = (int*)  (ws + 135168);
  unsigned short* xbf = (unsigned short*)(ws + 167936);             // 4 MB
  unsigned short* act = (unsigned short*)(ws + 167936 + 4194304);   // 12 MB
  float* contrib = (float*)(ws + 167936 + 4194304 + 12582912);      // 64 MB
  size_t need_full = (size_t)167936 + 4194304 + 12582912 + 67108864;
  int atomicMode = (ws_size < need_full) ? 1 : 0;

  k_convert_x<<<1024, 256, 0, stream>>>(x, xbf);
  k_router   <<<1024, 256, 0, stream>>>(x, gw, top_idx, top_w);
  k_hist     <<<1,    256, 0, stream>>>(top_idx, offs);
  k_compact  <<<64,   256, 0, stream>>>(top_idx, top_w, offs, list_t, list_w, slot_of);
  k_gateup   <<<dim3(INTER / 32, NEXP), 256, 0, stream>>>(xbf, wgp, wup, offs, list_t, list_w, act);
  if (atomicMode){
    hipMemsetAsync(d_out, 0, (size_t)out_size * sizeof(float), stream);
    k_down  <<<dim3(HID / 64, NEXP), 256, 0, stream>>>(act, wdp, offs, list_t, contrib, out, 1);
  } else {
    k_down  <<<dim3(HID / 64, NEXP), 256, 0, stream>>>(act, wdp, offs, list_t, contrib, out, 0);
    k_reduce<<<2048, 256, 0, stream>>>(contrib, slot_of, out);
  }
}